// Round 1
// baseline (236.616 us; speedup 1.0000x reference)
//
#include <hip/hip_runtime.h>
#include <hip/hip_bf16.h>

#define NB 16384
#define DIN 512
#define H1 256
#define H2 128
#define NE 18
#define NT 3
#define NGH 64
#define NETOT 14

typedef float f32x4 __attribute__((ext_vector_type(4)));
typedef short s16x8 __attribute__((ext_vector_type(8)));
typedef unsigned short u16;
typedef unsigned int u32;

__device__ __forceinline__ u16 f2bf(float f) {
    union { float f; u32 u; } v; v.f = f;
    u32 r = v.u + 0x7fffu + ((v.u >> 16) & 1u);
    return (u16)(r >> 16);
}
__device__ __forceinline__ float bf2f(u16 u) {
    union { u32 u; float f; } v; v.u = ((u32)u) << 16;
    return v.f;
}

// ---------------- prep: x fp32 -> bf16 ----------------
__global__ __launch_bounds__(256) void k_cvt_x(const float* __restrict__ x, u16* __restrict__ xb) {
    int i = (blockIdx.x * 256 + threadIdx.x) * 4;
    float4 v = *reinterpret_cast<const float4*>(x + i);
    ushort4 o;
    o.x = f2bf(v.x); o.y = f2bf(v.y); o.z = f2bf(v.z); o.w = f2bf(v.w);
    *reinterpret_cast<ushort4*>(xb + i) = o;
}

// ---------------- prep: transpose+convert W [e][K][N] -> [e][N][K] bf16 ----------------
__global__ __launch_bounds__(256) void k_transpose_cvt(const float* __restrict__ src, u16* __restrict__ dst,
                                                       int K, int N, int ntk, int ntn) {
    __shared__ float lds[64 * 65];
    int bx = blockIdx.x;
    int per = ntk * ntn;
    int e = bx / per, r = bx % per;
    int k0 = (r / ntn) * 64, n0 = (r % ntn) * 64;
    const float* s = src + (size_t)e * K * N;
    u16* d = dst + (size_t)e * N * K;
    int t = threadIdx.x;
#pragma unroll
    for (int i = 0; i < 16; ++i) {
        int idx = i * 256 + t;
        int kk = idx >> 6, nn = idx & 63;
        lds[kk * 65 + nn] = s[(size_t)(k0 + kk) * N + n0 + nn];
    }
    __syncthreads();
#pragma unroll
    for (int i = 0; i < 16; ++i) {
        int idx = i * 256 + t;
        int nn = idx >> 6, kk = idx & 63;
        d[(size_t)(n0 + nn) * K + k0 + kk] = f2bf(lds[kk * 65 + nn]);
    }
}

// ---------------- fused 2-layer expert kernel ----------------
// grid: 18 experts * 256 row-blocks (64 rows each); 512 threads (8 waves)
__global__ __launch_bounds__(512, 2) void k_expert(
    const u16* __restrict__ xb, const u16* __restrict__ w1t, const u16* __restrict__ w2t,
    const float* __restrict__ sb1, const float* __restrict__ db1, const float* __restrict__ tb1,
    const float* __restrict__ sb2, const float* __restrict__ db2, const float* __restrict__ tb2,
    u16* __restrict__ eout)
{
    // phase1: xs [64][72] @0 (4608), w1s [256][72] @4608 (18432)  -> 23040 u16
    // phase2: hs [64][264] @0 (16896), w2s [128][72] @16896 (9216) -> 26112 u16 (52.2KB)
    __shared__ u16 lds[26112];
    u16* xs  = lds;
    u16* w1s = lds + 4608;
    u16* hs  = lds;
    u16* w2s = lds + 16896;

    int bx = blockIdx.x;
    int e  = bx >> 8;
    int m0 = (bx & 255) * 64;
    int tid = threadIdx.x;
    int w = tid >> 6, lane = tid & 63;
    int wm = w & 1, wn = w >> 1;         // 2 x 4 wave grid
    int l15 = lane & 15, lk = (lane >> 4) * 8, lr4 = (lane >> 4) * 4;

    const float* b1p = (e < 4) ? sb1 + e * H1 : (e < 12) ? db1 + (e - 4) * H1 : tb1 + (e - 12) * H1;
    const float* b2p = (e < 4) ? sb2 + e * H2 : (e < 12) ? db2 + (e - 4) * H2 : tb2 + (e - 12) * H2;

    f32x4 acc1[2][4];
#pragma unroll
    for (int i = 0; i < 2; ++i)
#pragma unroll
        for (int j = 0; j < 4; ++j) acc1[i][j] = (f32x4)0.f;

    const u16* xg  = xb + (size_t)m0 * DIN;
    const u16* w1g = w1t + (size_t)e * H1 * DIN;
    int srow = tid >> 3, su = (tid & 7) * 8;

    // ---- GEMM1: h[64,256] = x[64,512] @ W1[512,256] ----
    for (int kc = 0; kc < DIN / 64; ++kc) {
        *reinterpret_cast<uint4*>(&xs[srow * 72 + su]) =
            *reinterpret_cast<const uint4*>(xg + (size_t)srow * DIN + kc * 64 + su);
#pragma unroll
        for (int it = 0; it < 4; ++it) {
            int rr = srow + it * 64;
            *reinterpret_cast<uint4*>(&w1s[rr * 72 + su]) =
                *reinterpret_cast<const uint4*>(w1g + (size_t)rr * DIN + kc * 64 + su);
        }
        __syncthreads();
        s16x8 af[2][2], bf[4][2];
#pragma unroll
        for (int mi = 0; mi < 2; ++mi)
#pragma unroll
            for (int kk = 0; kk < 2; ++kk)
                af[mi][kk] = *reinterpret_cast<const s16x8*>(&xs[(wm * 32 + mi * 16 + l15) * 72 + kk * 32 + lk]);
#pragma unroll
        for (int nj = 0; nj < 4; ++nj)
#pragma unroll
            for (int kk = 0; kk < 2; ++kk)
                bf[nj][kk] = *reinterpret_cast<const s16x8*>(&w1s[(wn * 64 + nj * 16 + l15) * 72 + kk * 32 + lk]);
#pragma unroll
        for (int kk = 0; kk < 2; ++kk)
#pragma unroll
            for (int mi = 0; mi < 2; ++mi)
#pragma unroll
                for (int nj = 0; nj < 4; ++nj)
                    acc1[mi][nj] = __builtin_amdgcn_mfma_f32_16x16x32_bf16(af[mi][kk], bf[nj][kk], acc1[mi][nj], 0, 0, 0);
        __syncthreads();
    }

    // ---- h = relu(acc1 + b1) -> LDS bf16 [64][264] ----
#pragma unroll
    for (int mi = 0; mi < 2; ++mi)
#pragma unroll
        for (int nj = 0; nj < 4; ++nj) {
            int col = wn * 64 + nj * 16 + l15;
            float bias = b1p[col];
#pragma unroll
            for (int r = 0; r < 4; ++r) {
                int row = wm * 32 + mi * 16 + lr4 + r;
                float v = acc1[mi][nj][r] + bias;
                hs[row * 264 + col] = f2bf(v > 0.f ? v : 0.f);
            }
        }
    __syncthreads();

    // ---- GEMM2: o[64,128] = h[64,256] @ W2[256,128] ----
    f32x4 acc2[2][2];
#pragma unroll
    for (int i = 0; i < 2; ++i)
#pragma unroll
        for (int j = 0; j < 2; ++j) acc2[i][j] = (f32x4)0.f;
    const u16* w2g = w2t + (size_t)e * H2 * H1;
    for (int kc = 0; kc < H1 / 64; ++kc) {
#pragma unroll
        for (int it = 0; it < 2; ++it) {
            int rr = srow + it * 64;
            *reinterpret_cast<uint4*>(&w2s[rr * 72 + su]) =
                *reinterpret_cast<const uint4*>(w2g + (size_t)rr * H1 + kc * 64 + su);
        }
        __syncthreads();
        s16x8 af[2][2], bf[2][2];
#pragma unroll
        for (int mi = 0; mi < 2; ++mi)
#pragma unroll
            for (int kk = 0; kk < 2; ++kk)
                af[mi][kk] = *reinterpret_cast<const s16x8*>(&hs[(wm * 32 + mi * 16 + l15) * 264 + kc * 64 + kk * 32 + lk]);
#pragma unroll
        for (int nj = 0; nj < 2; ++nj)
#pragma unroll
            for (int kk = 0; kk < 2; ++kk)
                bf[nj][kk] = *reinterpret_cast<const s16x8*>(&w2s[(wn * 32 + nj * 16 + l15) * 72 + kk * 32 + lk]);
#pragma unroll
        for (int kk = 0; kk < 2; ++kk)
#pragma unroll
            for (int mi = 0; mi < 2; ++mi)
#pragma unroll
                for (int nj = 0; nj < 2; ++nj)
                    acc2[mi][nj] = __builtin_amdgcn_mfma_f32_16x16x32_bf16(af[mi][kk], bf[nj][kk], acc2[mi][nj], 0, 0, 0);
        __syncthreads();
    }

    // ---- write expert out (bf16), [e][b][h] ----
    u16* eo = eout + ((size_t)e * NB + m0) * H2;
#pragma unroll
    for (int mi = 0; mi < 2; ++mi)
#pragma unroll
        for (int nj = 0; nj < 2; ++nj) {
            int col = wn * 32 + nj * 16 + l15;
            float bias = b2p[col];
#pragma unroll
            for (int r = 0; r < 4; ++r) {
                int row = wm * 32 + mi * 16 + lr4 + r;
                float v = acc2[mi][nj][r] + bias;
                eo[(size_t)row * H2 + col] = f2bf(v > 0.f ? v : 0.f);
            }
        }
}

// ---------------- gate kernel: gh=relu(x@gW1+gb1); gates=softmax(gh@gW2+gb2) ----------------
// grid: 256 blocks x 64 rows; 256 threads (4 waves)
__global__ __launch_bounds__(256) void k_gate(
    const u16* __restrict__ xb, const u16* __restrict__ gw1t,
    const float* __restrict__ gb1, const float* __restrict__ gw2, const float* __restrict__ gb2,
    float* __restrict__ gates)
{
    // phase1: xs [64][72] @0 (4608 u16), g1s [192][72] @4608 (13824 u16) = 36864 B
    // phase2: ghs [64][200] fp32 = 51200 B
    __shared__ __align__(16) char smem[51200];
    u16* xs  = reinterpret_cast<u16*>(smem);
    u16* g1s = reinterpret_cast<u16*>(smem) + 4608;
    float* ghs = reinterpret_cast<float*>(smem);

    int m0 = blockIdx.x * 64;
    int tid = threadIdx.x;
    int w = tid >> 6, lane = tid & 63;
    int wm = w & 1, wn = w >> 1;         // 2 x 2 wave grid; wave tile 32x96
    int l15 = lane & 15, lk = (lane >> 4) * 8, lr4 = (lane >> 4) * 4;

    f32x4 acc[2][6];
#pragma unroll
    for (int i = 0; i < 2; ++i)
#pragma unroll
        for (int j = 0; j < 6; ++j) acc[i][j] = (f32x4)0.f;

    const u16* xg = xb + (size_t)m0 * DIN;
    int srow = tid >> 3, su = (tid & 7) * 8;
    for (int kc = 0; kc < DIN / 64; ++kc) {
#pragma unroll
        for (int it = 0; it < 2; ++it) {
            int rr = srow + it * 32;
            *reinterpret_cast<uint4*>(&xs[rr * 72 + su]) =
                *reinterpret_cast<const uint4*>(xg + (size_t)rr * DIN + kc * 64 + su);
        }
#pragma unroll
        for (int it = 0; it < 6; ++it) {
            int rr = srow + it * 32;
            *reinterpret_cast<uint4*>(&g1s[rr * 72 + su]) =
                *reinterpret_cast<const uint4*>(gw1t + (size_t)rr * DIN + kc * 64 + su);
        }
        __syncthreads();
        s16x8 af[2][2], bfr[6][2];
#pragma unroll
        for (int mi = 0; mi < 2; ++mi)
#pragma unroll
            for (int kk = 0; kk < 2; ++kk)
                af[mi][kk] = *reinterpret_cast<const s16x8*>(&xs[(wm * 32 + mi * 16 + l15) * 72 + kk * 32 + lk]);
#pragma unroll
        for (int nj = 0; nj < 6; ++nj)
#pragma unroll
            for (int kk = 0; kk < 2; ++kk)
                bfr[nj][kk] = *reinterpret_cast<const s16x8*>(&g1s[(wn * 96 + nj * 16 + l15) * 72 + kk * 32 + lk]);
#pragma unroll
        for (int kk = 0; kk < 2; ++kk)
#pragma unroll
            for (int mi = 0; mi < 2; ++mi)
#pragma unroll
                for (int nj = 0; nj < 6; ++nj)
                    acc[mi][nj] = __builtin_amdgcn_mfma_f32_16x16x32_bf16(af[mi][kk], bfr[nj][kk], acc[mi][nj], 0, 0, 0);
        __syncthreads();
    }
    // gh -> LDS fp32 [64][200]
#pragma unroll
    for (int mi = 0; mi < 2; ++mi)
#pragma unroll
        for (int nj = 0; nj < 6; ++nj) {
            int col = wn * 96 + nj * 16 + l15;
            float bias = gb1[col];
#pragma unroll
            for (int r = 0; r < 4; ++r) {
                int row = wm * 32 + mi * 16 + lr4 + r;
                float v = acc[mi][nj][r] + bias;
                ghs[row * 200 + col] = v > 0.f ? v : 0.f;
            }
        }
    __syncthreads();

    // second layer + softmax: thread t<192 -> (task tt, row rr)
    if (tid < 192) {
        int tt = tid >> 6, rr = tid & 63;
        float logit[NETOT];
#pragma unroll
        for (int e2 = 0; e2 < NETOT; ++e2) logit[e2] = gb2[tt * NETOT + e2];
        const float* g2 = gw2 + tt * NGH * NETOT;
        const float* gr = &ghs[rr * 200 + tt * 64];
        for (int g = 0; g < NGH; ++g) {
            float v = gr[g];
#pragma unroll
            for (int e2 = 0; e2 < NETOT; ++e2) logit[e2] += v * g2[g * NETOT + e2];
        }
        float m = logit[0];
#pragma unroll
        for (int e2 = 1; e2 < NETOT; ++e2) m = fmaxf(m, logit[e2]);
        float s = 0.f, p[NETOT];
#pragma unroll
        for (int e2 = 0; e2 < NETOT; ++e2) { p[e2] = __expf(logit[e2] - m); s += p[e2]; }
        float inv = 1.f / s;
        float* go = gates + (size_t)(m0 + rr) * (NT * NETOT) + tt * NETOT;
#pragma unroll
        for (int e2 = 0; e2 < NETOT; ++e2) go[e2] = p[e2] * inv;
    }
}

// ---------------- combine: out[t][b][h] = sum_e gate * expert ----------------
__global__ __launch_bounds__(256) void k_combine(
    const u16* __restrict__ eout, const float* __restrict__ gates, float* __restrict__ out)
{
    int tid = threadIdx.x;
    int lr = tid >> 5, hq = tid & 31;
    int b = blockIdx.x * 8 + lr;
    int h0 = hq * 4;
    const float* g = gates + (size_t)b * (NT * NETOT);
    float o0[4] = {0, 0, 0, 0}, o1[4] = {0, 0, 0, 0}, o2[4] = {0, 0, 0, 0};
#pragma unroll
    for (int e = 0; e < NE; ++e) {
        ushort4 ev = *reinterpret_cast<const ushort4*>(&eout[((size_t)e * NB + b) * H2 + h0]);
        float v0 = bf2f(ev.x), v1 = bf2f(ev.y), v2 = bf2f(ev.z), v3 = bf2f(ev.w);
        if (e < 12) {
            float wa = g[e], wb = g[NETOT + e], wc = g[2 * NETOT + e];
            o0[0] += wa * v0; o0[1] += wa * v1; o0[2] += wa * v2; o0[3] += wa * v3;
            o1[0] += wb * v0; o1[1] += wb * v1; o1[2] += wb * v2; o1[3] += wb * v3;
            o2[0] += wc * v0; o2[1] += wc * v1; o2[2] += wc * v2; o2[3] += wc * v3;
        } else {
            int t = (e - 12) >> 1, te = (e - 12) & 1;
            float wt = g[t * NETOT + 12 + te];
            float* ot = (t == 0) ? o0 : (t == 1) ? o1 : o2;
            ot[0] += wt * v0; ot[1] += wt * v1; ot[2] += wt * v2; ot[3] += wt * v3;
        }
    }
    size_t base = (size_t)b * H2 + h0;
    *reinterpret_cast<float4*>(&out[0 * (size_t)NB * H2 + base]) = make_float4(o0[0], o0[1], o0[2], o0[3]);
    *reinterpret_cast<float4*>(&out[1 * (size_t)NB * H2 + base]) = make_float4(o1[0], o1[1], o1[2], o1[3]);
    *reinterpret_cast<float4*>(&out[2 * (size_t)NB * H2 + base]) = make_float4(o2[0], o2[1], o2[2], o2[3]);
}

extern "C" void kernel_launch(void* const* d_in, const int* in_sizes, int n_in,
                              void* d_out, int out_size, void* d_ws, size_t ws_size,
                              hipStream_t stream)
{
    const float* x   = (const float*)d_in[0];
    const float* sW1 = (const float*)d_in[2];
    const float* sb1 = (const float*)d_in[3];
    const float* sW2 = (const float*)d_in[4];
    const float* sb2 = (const float*)d_in[5];
    const float* dW1 = (const float*)d_in[6];
    const float* db1 = (const float*)d_in[7];
    const float* dW2 = (const float*)d_in[8];
    const float* db2 = (const float*)d_in[9];
    const float* tW1 = (const float*)d_in[10];
    const float* tb1 = (const float*)d_in[11];
    const float* tW2 = (const float*)d_in[12];
    const float* tb2 = (const float*)d_in[13];
    const float* gW1 = (const float*)d_in[14];
    const float* gb1 = (const float*)d_in[15];
    const float* gW2 = (const float*)d_in[16];
    const float* gb2 = (const float*)d_in[17];

    char* ws = (char*)d_ws;
    u16*  xb    = (u16*)(ws + 0);               // 16,777,216 B
    u16*  w1t   = (u16*)(ws + 16777216);        //  4,718,592 B
    u16*  w2t   = (u16*)(ws + 21495808);        //  1,179,648 B
    u16*  gw1t  = (u16*)(ws + 22675456);        //    196,608 B
    float* gates = (float*)(ws + 22872064);     //  2,752,512 B
    u16*  eout  = (u16*)(ws + 25624576);        // 75,497,472 B -> total ~101.1 MB

    k_cvt_x<<<dim3(NB * DIN / 1024), dim3(256), 0, stream>>>(x, xb);

    k_transpose_cvt<<<dim3(4 * 32), dim3(256), 0, stream>>>(sW1, w1t, 512, 256, 8, 4);
    k_transpose_cvt<<<dim3(8 * 32), dim3(256), 0, stream>>>(dW1, w1t + (size_t)4 * 256 * 512, 512, 256, 8, 4);
    k_transpose_cvt<<<dim3(6 * 32), dim3(256), 0, stream>>>(tW1, w1t + (size_t)12 * 256 * 512, 512, 256, 8, 4);
    k_transpose_cvt<<<dim3(4 * 8), dim3(256), 0, stream>>>(sW2, w2t, 256, 128, 4, 2);
    k_transpose_cvt<<<dim3(8 * 8), dim3(256), 0, stream>>>(dW2, w2t + (size_t)4 * 128 * 256, 256, 128, 4, 2);
    k_transpose_cvt<<<dim3(6 * 8), dim3(256), 0, stream>>>(tW2, w2t + (size_t)12 * 128 * 256, 256, 128, 4, 2);
    k_transpose_cvt<<<dim3(3 * 8), dim3(256), 0, stream>>>(gW1, gw1t, 512, 64, 8, 1);

    k_gate<<<dim3(NB / 64), dim3(256), 0, stream>>>(xb, gw1t, gb1, gW2, gb2, gates);
    k_expert<<<dim3(NE * (NB / 64)), dim3(512), 0, stream>>>(xb, w1t, w2t, sb1, db1, tb1, sb2, db2, tb2, eout);
    k_combine<<<dim3(NB / 8), dim3(256), 0, stream>>>(eout, gates, (float*)d_out);
}

// Round 3
// 196.905 us; speedup vs baseline: 1.2017x; 1.2017x over previous
//
#include <hip/hip_runtime.h>
#include <hip/hip_bf16.h>

#define NB 16384
#define DIN 512
#define H1 256
#define H2 128
#define NE 18
#define NT 3
#define NGH 64
#define NETOT 14

typedef float f32x4 __attribute__((ext_vector_type(4)));
typedef short s16x8 __attribute__((ext_vector_type(8)));
typedef unsigned short u16;
typedef unsigned int u32;

__device__ __forceinline__ u16 f2bf(float f) {
    union { float f; u32 u; } v; v.f = f;
    u32 r = v.u + 0x7fffu + ((v.u >> 16) & 1u);
    return (u16)(r >> 16);
}
__device__ __forceinline__ float bf2f(u16 u) {
    union { u32 u; float f; } v; v.u = ((u32)u) << 16;
    return v.f;
}

// async global->LDS, 16B per lane. lds ptr must be wave-uniform; HW writes lane i at lds+16*i.
#define GLDS16(g, l) __builtin_amdgcn_global_load_lds((const u32*)(g), (u32*)(l), 16, 0, 0)

// ---------------- prep: x fp32 -> bf16 ----------------
__global__ __launch_bounds__(256) void k_cvt_x(const float* __restrict__ x, u16* __restrict__ xb) {
    int i = (blockIdx.x * 256 + threadIdx.x) * 4;
    float4 v = *reinterpret_cast<const float4*>(x + i);
    ushort4 o;
    o.x = f2bf(v.x); o.y = f2bf(v.y); o.z = f2bf(v.z); o.w = f2bf(v.w);
    *reinterpret_cast<ushort4*>(xb + i) = o;
}

// ---------------- prep: ALL weight transposes in one launch ----------------
__global__ __launch_bounds__(256) void k_transpose_all(
    const float* __restrict__ sW1, const float* __restrict__ dW1, const float* __restrict__ tW1,
    const float* __restrict__ sW2, const float* __restrict__ dW2, const float* __restrict__ tW2,
    const float* __restrict__ gW1, u16* __restrict__ w1t, u16* __restrict__ w2t, u16* __restrict__ gw1t)
{
    __shared__ float lds[64 * 65];
    int b = blockIdx.x;
    const float* src; u16* dst; int K, N, k0, n0;
    if (b < 576) {
        int e = b >> 5, tile = b & 31;
        src = (e < 4) ? sW1 + (size_t)e * DIN * H1 : (e < 12) ? dW1 + (size_t)(e - 4) * DIN * H1
                                                              : tW1 + (size_t)(e - 12) * DIN * H1;
        dst = w1t + (size_t)e * H1 * DIN; K = DIN; N = H1;
        k0 = (tile >> 2) * 64; n0 = (tile & 3) * 64;
    } else if (b < 720) {
        int b2 = b - 576; int e = b2 >> 3, tile = b2 & 7;
        src = (e < 4) ? sW2 + (size_t)e * H1 * H2 : (e < 12) ? dW2 + (size_t)(e - 4) * H1 * H2
                                                             : tW2 + (size_t)(e - 12) * H1 * H2;
        dst = w2t + (size_t)e * H2 * H1; K = H1; N = H2;
        k0 = (tile >> 1) * 64; n0 = (tile & 1) * 64;
    } else {
        int b3 = b - 720; int t = b3 >> 3, tile = b3 & 7;
        src = gW1 + (size_t)t * DIN * NGH; dst = gw1t + (size_t)t * NGH * DIN; K = DIN; N = NGH;
        k0 = tile * 64; n0 = 0;
    }
    int t = threadIdx.x;
#pragma unroll
    for (int i = 0; i < 16; ++i) {
        int idx = i * 256 + t;
        int kk = idx >> 6, nn = idx & 63;
        lds[kk * 65 + nn] = src[(size_t)(k0 + kk) * N + n0 + nn];
    }
    __syncthreads();
#pragma unroll
    for (int i = 0; i < 16; ++i) {
        int idx = i * 256 + t;
        int nn = idx >> 6, kk = idx & 63;
        dst[(size_t)(n0 + nn) * K + k0 + kk] = f2bf(lds[kk * 65 + nn]);
    }
}

// ---------------- fused 2-layer expert kernel (m97-style) ----------------
// grid: 18 experts * 128 m-blocks (128 rows). 512 threads = 8 waves (2M x 4N).
__global__ __launch_bounds__(512, 2) void k_expert(
    const u16* __restrict__ xb, const u16* __restrict__ w1t, const u16* __restrict__ w2t,
    const float* __restrict__ sb1, const float* __restrict__ db1, const float* __restrict__ tb1,
    const float* __restrict__ sb2, const float* __restrict__ db2, const float* __restrict__ tb2,
    u16* __restrict__ eout)
{
    // LDS map (bytes):
    //  phase1: xs[buf] @ buf*16384 (2x16KB), w1s[buf] @ 32768 + buf*32768 (2x32KB)  -> [0,96K)
    //  phase2: hs @ 0 (64KB, [128][256] swizzled), w2s[buf] @ 65536 + buf*16384 (2x16KB)
    __shared__ __align__(128) char smem[98304];

    const int bx = blockIdx.x;
    const int e  = bx >> 7;
    const int m0 = (bx & 127) * 128;
    const int tid = threadIdx.x;
    const int w = tid >> 6, lane = tid & 63;
    const int wm = w & 1, wn = w >> 1;      // 2M x 4N
    const int l15 = lane & 15, q = lane >> 4;
    const int q16 = q * 16;
    const int srow8 = lane >> 3, sslot = lane & 7;

    const u16* xg  = xb + (size_t)m0 * DIN;
    const u16* w1g = w1t + (size_t)e * H1 * DIN;
    const u16* w2g = w2t + (size_t)e * H2 * H1;
    const float* b1p = (e < 4) ? sb1 + e * H1 : (e < 12) ? db1 + (e - 4) * H1 : tb1 + (e - 12) * H1;
    const float* b2p = (e < 4) ? sb2 + e * H2 : (e < 12) ? db2 + (e - 4) * H2 : tb2 + (e - 12) * H2;

    // ---- precomputed staging addresses (per-lane global, wave-uniform LDS) ----
    const u16* gx[2]; int lx[2];
    const u16* gw1[4]; int lw1[4];
    const u16* gw2[2]; int lw2[2];
#pragma unroll
    for (int j = 0; j < 2; ++j) {
        int r0 = (w * 2 + j) * 8, row = r0 + srow8;
        gx[j] = xg + (size_t)row * DIN + ((sslot ^ (row & 7)) * 8);
        lx[j] = r0 * 128;
        int rw0 = (w * 2 + j) * 8, roww = rw0 + srow8;
        gw2[j] = w2g + (size_t)roww * H1 + ((sslot ^ (roww & 7)) * 8);
        lw2[j] = 65536 + rw0 * 128;
    }
#pragma unroll
    for (int j = 0; j < 4; ++j) {
        int r0 = (w * 4 + j) * 8, row = r0 + srow8;
        gw1[j] = w1g + (size_t)row * DIN + ((sslot ^ (row & 7)) * 8);
        lw1[j] = 32768 + r0 * 128;
    }

    // ---- fragment read bases ----
    int baseA[4], swA[4], baseB[4], swB[4], baseB2[2], swB2[2], baseA2[4], swA2[4];
#pragma unroll
    for (int mi = 0; mi < 4; ++mi) {
        int r = wm * 64 + mi * 16 + l15;
        baseA[mi] = r * 128; swA[mi] = (r & 7) << 4;
        baseA2[mi] = r * 512; swA2[mi] = ((r >> 1) & 7) << 4;
    }
#pragma unroll
    for (int nj = 0; nj < 4; ++nj) {
        int r = wn * 64 + nj * 16 + l15;
        baseB[nj] = r * 128; swB[nj] = (r & 7) << 4;
    }
#pragma unroll
    for (int nj = 0; nj < 2; ++nj) {
        int r = wn * 32 + nj * 16 + l15;
        baseB2[nj] = r * 128; swB2[nj] = (r & 7) << 4;
    }

    f32x4 acc1[4][4];
#pragma unroll
    for (int i = 0; i < 4; ++i)
#pragma unroll
        for (int j = 0; j < 4; ++j) acc1[i][j] = (f32x4)0.f;

    // ---- GEMM1: h[128,256] = x[128,512] @ W1t[256,512]^T, 8 chunks of BK=64 ----
    {
#pragma unroll
        for (int j = 0; j < 2; ++j) GLDS16(gx[j], smem + lx[j]);
#pragma unroll
        for (int j = 0; j < 4; ++j) GLDS16(gw1[j], smem + lw1[j]);
        __syncthreads();
        int cur = 0;
        for (int kc = 0; kc < 8; ++kc) {
            if (kc < 7) {
                int nb = cur ^ 1, ko = (kc + 1) * 64;
#pragma unroll
                for (int j = 0; j < 2; ++j) GLDS16(gx[j] + ko, smem + nb * 16384 + lx[j]);
#pragma unroll
                for (int j = 0; j < 4; ++j) GLDS16(gw1[j] + ko, smem + nb * 32768 + lw1[j]);
            }
            const int xo = cur * 16384;
            const int wo = 32768 + cur * 32768;   // BUGFIX: w1s region base was missing
#pragma unroll
            for (int kk = 0; kk < 2; ++kk) {
                const int kb = kk * 64 + q16;
                s16x8 af[4], bf[4];
#pragma unroll
                for (int mi = 0; mi < 4; ++mi)
                    af[mi] = *(const s16x8*)(smem + xo + baseA[mi] + (kb ^ swA[mi]));
#pragma unroll
                for (int nj = 0; nj < 4; ++nj)
                    bf[nj] = *(const s16x8*)(smem + wo + baseB[nj] + (kb ^ swB[nj]));
#pragma unroll
                for (int mi = 0; mi < 4; ++mi)
#pragma unroll
                    for (int nj = 0; nj < 4; ++nj)
                        acc1[mi][nj] = __builtin_amdgcn_mfma_f32_16x16x32_bf16(af[mi], bf[nj], acc1[mi][nj], 0, 0, 0);
            }
            __syncthreads();
            cur ^= 1;
        }
    }

    // ---- stage W2 chunk 0 (into [64K,80K), dead region), then write h to LDS ----
#pragma unroll
    for (int j = 0; j < 2; ++j) GLDS16(gw2[j], smem + lw2[j]);
#pragma unroll
    for (int mi = 0; mi < 4; ++mi)
#pragma unroll
        for (int nj = 0; nj < 4; ++nj) {
            int col = wn * 64 + nj * 16 + l15;
            float bias = b1p[col];
#pragma unroll
            for (int r = 0; r < 4; ++r) {
                int row = wm * 64 + mi * 16 + q * 4 + r;
                float v = acc1[mi][nj][r] + bias;
                *(u16*)(smem + row * 512 + ((col * 2) ^ (((row >> 1) & 7) << 4))) = f2bf(v > 0.f ? v : 0.f);
            }
        }
    __syncthreads();

    // ---- GEMM2: o[128,128] = h[128,256] @ W2t[128,256]^T, 4 chunks of BK=64 ----
    f32x4 acc2[4][2];
#pragma unroll
    for (int i = 0; i < 4; ++i)
#pragma unroll
        for (int j = 0; j < 2; ++j) acc2[i][j] = (f32x4)0.f;
    int c2 = 0;
    for (int kc = 0; kc < 4; ++kc) {
        if (kc < 3) {
            int nb = c2 ^ 1, ko = (kc + 1) * 64;
#pragma unroll
            for (int j = 0; j < 2; ++j) GLDS16(gw2[j] + ko, smem + (nb ? 16384 : 0) + lw2[j]);
        }
        const int wo = c2 * 16384;
#pragma unroll
        for (int kk = 0; kk < 2; ++kk) {
            const int kb = kk * 64 + q16;
            const int khb = kc * 128 + kb;
            s16x8 a2[4], b2[2];
#pragma unroll
            for (int mi = 0; mi < 4; ++mi)
                a2[mi] = *(const s16x8*)(smem + baseA2[mi] + (khb ^ swA2[mi]));
#pragma unroll
            for (int nj = 0; nj < 2; ++nj)
                b2[nj] = *(const s16x8*)(smem + 65536 + wo + baseB2[nj] + (kb ^ swB2[nj]));
#pragma unroll
            for (int mi = 0; mi < 4; ++mi)
#pragma unroll
                for (int nj = 0; nj < 2; ++nj)
                    acc2[mi][nj] = __builtin_amdgcn_mfma_f32_16x16x32_bf16(a2[mi], b2[nj], acc2[mi][nj], 0, 0, 0);
        }
        __syncthreads();
        c2 ^= 1;
    }

    // ---- epilogue: relu(acc2 + b2) -> eout[e][b][h] bf16 ----
    u16* eo = eout + ((size_t)e * NB + m0) * H2;
#pragma unroll
    for (int mi = 0; mi < 4; ++mi)
#pragma unroll
        for (int nj = 0; nj < 2; ++nj) {
            int col = wn * 32 + nj * 16 + l15;
            float bias = b2p[col];
#pragma unroll
            for (int r = 0; r < 4; ++r) {
                int row = wm * 64 + mi * 16 + q * 4 + r;
                float v = acc2[mi][nj][r] + bias;
                eo[(size_t)row * H2 + col] = f2bf(v > 0.f ? v : 0.f);
            }
        }
}

// ---------------- gate kernel ----------------
__global__ __launch_bounds__(256) void k_gate(
    const u16* __restrict__ xb, const u16* __restrict__ gw1t,
    const float* __restrict__ gb1, const float* __restrict__ gw2, const float* __restrict__ gb2,
    float* __restrict__ gates)
{
    __shared__ __align__(16) char smem[51200];
    u16* xs  = reinterpret_cast<u16*>(smem);
    u16* g1s = reinterpret_cast<u16*>(smem) + 4608;
    float* ghs = reinterpret_cast<float*>(smem);

    int m0 = blockIdx.x * 64;
    int tid = threadIdx.x;
    int w = tid >> 6, lane = tid & 63;
    int wm = w & 1, wn = w >> 1;
    int l15 = lane & 15, lk = (lane >> 4) * 8, lr4 = (lane >> 4) * 4;

    f32x4 acc[2][6];
#pragma unroll
    for (int i = 0; i < 2; ++i)
#pragma unroll
        for (int j = 0; j < 6; ++j) acc[i][j] = (f32x4)0.f;

    const u16* xg = xb + (size_t)m0 * DIN;
    int srow = tid >> 3, su = (tid & 7) * 8;
    for (int kc = 0; kc < DIN / 64; ++kc) {
#pragma unroll
        for (int it = 0; it < 2; ++it) {
            int rr = srow + it * 32;
            *reinterpret_cast<uint4*>(&xs[rr * 72 + su]) =
                *reinterpret_cast<const uint4*>(xg + (size_t)rr * DIN + kc * 64 + su);
        }
#pragma unroll
        for (int it = 0; it < 6; ++it) {
            int rr = srow + it * 32;
            *reinterpret_cast<uint4*>(&g1s[rr * 72 + su]) =
                *reinterpret_cast<const uint4*>(gw1t + (size_t)rr * DIN + kc * 64 + su);
        }
        __syncthreads();
        s16x8 af[2][2], bfr[6][2];
#pragma unroll
        for (int mi = 0; mi < 2; ++mi)
#pragma unroll
            for (int kk = 0; kk < 2; ++kk)
                af[mi][kk] = *reinterpret_cast<const s16x8*>(&xs[(wm * 32 + mi * 16 + l15) * 72 + kk * 32 + lk]);
#pragma unroll
        for (int nj = 0; nj < 6; ++nj)
#pragma unroll
            for (int kk = 0; kk < 2; ++kk)
                bfr[nj][kk] = *reinterpret_cast<const s16x8*>(&g1s[(wn * 96 + nj * 16 + l15) * 72 + kk * 32 + lk]);
#pragma unroll
        for (int kk = 0; kk < 2; ++kk)
#pragma unroll
            for (int mi = 0; mi < 2; ++mi)
#pragma unroll
                for (int nj = 0; nj < 6; ++nj)
                    acc[mi][nj] = __builtin_amdgcn_mfma_f32_16x16x32_bf16(af[mi][kk], bfr[nj][kk], acc[mi][nj], 0, 0, 0);
        __syncthreads();
    }
#pragma unroll
    for (int mi = 0; mi < 2; ++mi)
#pragma unroll
        for (int nj = 0; nj < 6; ++nj) {
            int col = wn * 96 + nj * 16 + l15;
            float bias = gb1[col];
#pragma unroll
            for (int r = 0; r < 4; ++r) {
                int row = wm * 32 + mi * 16 + lr4 + r;
                float v = acc[mi][nj][r] + bias;
                ghs[row * 200 + col] = v > 0.f ? v : 0.f;
            }
        }
    __syncthreads();

    if (tid < 192) {
        int tt = tid >> 6, rr = tid & 63;
        float logit[NETOT];
#pragma unroll
        for (int e2 = 0; e2 < NETOT; ++e2) logit[e2] = gb2[tt * NETOT + e2];
        const float* g2 = gw2 + tt * NGH * NETOT;
        const float* gr = &ghs[rr * 200 + tt * 64];
        for (int g = 0; g < NGH; ++g) {
            float v = gr[g];
#pragma unroll
            for (int e2 = 0; e2 < NETOT; ++e2) logit[e2] += v * g2[g * NETOT + e2];
        }
        float m = logit[0];
#pragma unroll
        for (int e2 = 1; e2 < NETOT; ++e2) m = fmaxf(m, logit[e2]);
        float s = 0.f, p[NETOT];
#pragma unroll
        for (int e2 = 0; e2 < NETOT; ++e2) { p[e2] = __expf(logit[e2] - m); s += p[e2]; }
        float inv = 1.f / s;
        float* go = gates + (size_t)(m0 + rr) * (NT * NETOT) + tt * NETOT;
#pragma unroll
        for (int e2 = 0; e2 < NETOT; ++e2) go[e2] = p[e2] * inv;
    }
}

// ---------------- combine ----------------
__global__ __launch_bounds__(256) void k_combine(
    const u16* __restrict__ eout, const float* __restrict__ gates, float* __restrict__ out)
{
    int tid = threadIdx.x;
    int lr = tid >> 5, hq = tid & 31;
    int b = blockIdx.x * 8 + lr;
    int h0 = hq * 4;
    const float* g = gates + (size_t)b * (NT * NETOT);
    float o0[4] = {0, 0, 0, 0}, o1[4] = {0, 0, 0, 0}, o2[4] = {0, 0, 0, 0};
#pragma unroll
    for (int e = 0; e < NE; ++e) {
        ushort4 ev = *reinterpret_cast<const ushort4*>(&eout[((size_t)e * NB + b) * H2 + h0]);
        float v0 = bf2f(ev.x), v1 = bf2f(ev.y), v2 = bf2f(ev.z), v3 = bf2f(ev.w);
        if (e < 12) {
            float wa = g[e], wb = g[NETOT + e], wc = g[2 * NETOT + e];
            o0[0] += wa * v0; o0[1] += wa * v1; o0[2] += wa * v2; o0[3] += wa * v3;
            o1[0] += wb * v0; o1[1] += wb * v1; o1[2] += wb * v2; o1[3] += wb * v3;
            o2[0] += wc * v0; o2[1] += wc * v1; o2[2] += wc * v2; o2[3] += wc * v3;
        } else {
            int t = (e - 12) >> 1, te = (e - 12) & 1;
            float wt = g[t * NETOT + 12 + te];
            float* ot = (t == 0) ? o0 : (t == 1) ? o1 : o2;
            ot[0] += wt * v0; ot[1] += wt * v1; ot[2] += wt * v2; ot[3] += wt * v3;
        }
    }
    size_t base = (size_t)b * H2 + h0;
    *reinterpret_cast<float4*>(&out[0 * (size_t)NB * H2 + base]) = make_float4(o0[0], o0[1], o0[2], o0[3]);
    *reinterpret_cast<float4*>(&out[1 * (size_t)NB * H2 + base]) = make_float4(o1[0], o1[1], o1[2], o1[3]);
    *reinterpret_cast<float4*>(&out[2 * (size_t)NB * H2 + base]) = make_float4(o2[0], o2[1], o2[2], o2[3]);
}

extern "C" void kernel_launch(void* const* d_in, const int* in_sizes, int n_in,
                              void* d_out, int out_size, void* d_ws, size_t ws_size,
                              hipStream_t stream)
{
    const float* x   = (const float*)d_in[0];
    const float* sW1 = (const float*)d_in[2];
    const float* sb1 = (const float*)d_in[3];
    const float* sW2 = (const float*)d_in[4];
    const float* sb2 = (const float*)d_in[5];
    const float* dW1 = (const float*)d_in[6];
    const float* db1 = (const float*)d_in[7];
    const float* dW2 = (const float*)d_in[8];
    const float* db2 = (const float*)d_in[9];
    const float* tW1 = (const float*)d_in[10];
    const float* tb1 = (const float*)d_in[11];
    const float* tW2 = (const float*)d_in[12];
    const float* tb2 = (const float*)d_in[13];
    const float* gW1 = (const float*)d_in[14];
    const float* gb1 = (const float*)d_in[15];
    const float* gW2 = (const float*)d_in[16];
    const float* gb2 = (const float*)d_in[17];

    char* ws = (char*)d_ws;
    u16*  xb    = (u16*)(ws + 0);
    u16*  w1t   = (u16*)(ws + 16777216);
    u16*  w2t   = (u16*)(ws + 21495808);
    u16*  gw1t  = (u16*)(ws + 22675456);
    float* gates = (float*)(ws + 22872064);
    u16*  eout  = (u16*)(ws + 25624576);

    k_cvt_x<<<dim3(NB * DIN / 1024), dim3(256), 0, stream>>>(x, xb);
    k_transpose_all<<<dim3(744), dim3(256), 0, stream>>>(sW1, dW1, tW1, sW2, dW2, tW2, gW1, w1t, w2t, gw1t);
    k_gate<<<dim3(NB / 64), dim3(256), 0, stream>>>(xb, gw1t, gb1, gW2, gb2, gates);
    k_expert<<<dim3(NE * (NB / 128)), dim3(512), 0, stream>>>(xb, w1t, w2t, sb1, db1, tb1, sb2, db2, tb2, eout);
    k_combine<<<dim3(NB / 8), dim3(256), 0, stream>>>(eout, gates, (float*)d_out);
}

// Round 4
// 186.149 us; speedup vs baseline: 1.2711x; 1.0578x over previous
//
#include <hip/hip_runtime.h>
#include <hip/hip_bf16.h>

#define NB 16384
#define DIN 512
#define H1 256
#define H2 128
#define NE 18
#define NT 3
#define NGH 64
#define NETOT 14

typedef float f32x4 __attribute__((ext_vector_type(4)));
typedef short s16x8 __attribute__((ext_vector_type(8)));
typedef unsigned short u16;
typedef unsigned int u32;

__device__ __forceinline__ u16 f2bf(float f) {
    union { float f; u32 u; } v; v.f = f;
    u32 r = v.u + 0x7fffu + ((v.u >> 16) & 1u);
    return (u16)(r >> 16);
}
__device__ __forceinline__ float bf2f(u16 u) {
    union { u32 u; float f; } v; v.u = ((u32)u) << 16;
    return v.f;
}

// async global->LDS, 16B per lane. lds ptr must be wave-uniform; HW writes lane i at lds+16*i.
#define GLDS16(g, l) __builtin_amdgcn_global_load_lds((const u32*)(g), (u32*)(l), 16, 0, 0)
// counted-wait barrier: drain our loads AFTER compute, then raw barrier (no compiler re-drain)
#define VMCNT0_BARRIER() do { asm volatile("s_waitcnt vmcnt(0)" ::: "memory"); __builtin_amdgcn_s_barrier(); } while (0)

// ---------------- prep: x cvt + ALL weight transposes, one launch ----------------
// blocks [0,8192): cvt x; [8192,8768): W1; [8768,8912): W2; [8912,8936): gW1
__global__ __launch_bounds__(256) void k_prep(
    const float* __restrict__ x, u16* __restrict__ xb,
    const float* __restrict__ sW1, const float* __restrict__ dW1, const float* __restrict__ tW1,
    const float* __restrict__ sW2, const float* __restrict__ dW2, const float* __restrict__ tW2,
    const float* __restrict__ gW1, u16* __restrict__ w1t, u16* __restrict__ w2t, u16* __restrict__ gw1t)
{
    __shared__ float lds[64 * 65];
    int bx = blockIdx.x;
    if (bx < 8192) {
        int i = (bx * 256 + threadIdx.x) * 4;
        float4 v = *reinterpret_cast<const float4*>(x + i);
        ushort4 o;
        o.x = f2bf(v.x); o.y = f2bf(v.y); o.z = f2bf(v.z); o.w = f2bf(v.w);
        *reinterpret_cast<ushort4*>(xb + i) = o;
        return;
    }
    int b = bx - 8192;
    const float* src; u16* dst; int K, N, k0, n0;
    if (b < 576) {
        int e = b >> 5, tile = b & 31;
        src = (e < 4) ? sW1 + (size_t)e * DIN * H1 : (e < 12) ? dW1 + (size_t)(e - 4) * DIN * H1
                                                              : tW1 + (size_t)(e - 12) * DIN * H1;
        dst = w1t + (size_t)e * H1 * DIN; K = DIN; N = H1;
        k0 = (tile >> 2) * 64; n0 = (tile & 3) * 64;
    } else if (b < 720) {
        int b2 = b - 576; int e = b2 >> 3, tile = b2 & 7;
        src = (e < 4) ? sW2 + (size_t)e * H1 * H2 : (e < 12) ? dW2 + (size_t)(e - 4) * H1 * H2
                                                             : tW2 + (size_t)(e - 12) * H1 * H2;
        dst = w2t + (size_t)e * H2 * H1; K = H1; N = H2;
        k0 = (tile >> 1) * 64; n0 = (tile & 1) * 64;
    } else {
        int b3 = b - 720; int t = b3 >> 3, tile = b3 & 7;
        src = gW1 + (size_t)t * DIN * NGH; dst = gw1t + (size_t)t * NGH * DIN; K = DIN; N = NGH;
        k0 = tile * 64; n0 = 0;
    }
    int t = threadIdx.x;
#pragma unroll
    for (int i = 0; i < 16; ++i) {
        int idx = i * 256 + t;
        int kk = idx >> 6, nn = idx & 63;
        lds[kk * 65 + nn] = src[(size_t)(k0 + kk) * N + n0 + nn];
    }
    __syncthreads();
#pragma unroll
    for (int i = 0; i < 16; ++i) {
        int idx = i * 256 + t;
        int nn = idx >> 6, kk = idx & 63;
        dst[(size_t)(n0 + nn) * K + k0 + kk] = f2bf(lds[kk * 65 + nn]);
    }
}

// ---------------- fused 2-layer expert kernel ----------------
// grid: 18 experts * 128 m-blocks (128 rows). 512 threads = 8 waves (2M x 4N).
// T3-minimal schedule: STAGE(next) -> compute(cur) -> vmcnt(0) -> raw barrier.
__global__ __launch_bounds__(512, 2) void k_expert(
    const u16* __restrict__ xb, const u16* __restrict__ w1t, const u16* __restrict__ w2t,
    const float* __restrict__ sb1, const float* __restrict__ db1, const float* __restrict__ tb1,
    const float* __restrict__ sb2, const float* __restrict__ db2, const float* __restrict__ tb2,
    u16* __restrict__ eout)
{
    // LDS map (bytes):
    //  phase1: xs[buf] @ buf*16384 (2x16KB), w1s[buf] @ 32768 + buf*32768 (2x32KB)  -> [0,96K)
    //  phase2: hs @ 0 (64KB, [128][256] swizzled), w2s[buf] @ 65536 + buf*16384 (2x16KB)
    __shared__ __align__(128) char smem[98304];

    const int bx = blockIdx.x;
    const int e  = bx >> 7;
    const int m0 = (bx & 127) * 128;
    const int tid = threadIdx.x;
    const int w = tid >> 6, lane = tid & 63;
    const int wm = w & 1, wn = w >> 1;      // 2M x 4N
    const int l15 = lane & 15, q = lane >> 4;
    const int q16 = q * 16;
    const int srow8 = lane >> 3, sslot = lane & 7;

    const u16* xg  = xb + (size_t)m0 * DIN;
    const u16* w1g = w1t + (size_t)e * H1 * DIN;
    const u16* w2g = w2t + (size_t)e * H2 * H1;
    const float* b1p = (e < 4) ? sb1 + e * H1 : (e < 12) ? db1 + (e - 4) * H1 : tb1 + (e - 12) * H1;
    const float* b2p = (e < 4) ? sb2 + e * H2 : (e < 12) ? db2 + (e - 4) * H2 : tb2 + (e - 12) * H2;

    // ---- precomputed staging addresses (per-lane global, wave-uniform LDS) ----
    const u16* gx[2]; int lx[2];
    const u16* gw1[4]; int lw1[4];
    const u16* gw2[2]; int lw2[2];
#pragma unroll
    for (int j = 0; j < 2; ++j) {
        int r0 = (w * 2 + j) * 8, row = r0 + srow8;
        gx[j] = xg + (size_t)row * DIN + ((sslot ^ (row & 7)) * 8);
        lx[j] = r0 * 128;
        int rw0 = (w * 2 + j) * 8, roww = rw0 + srow8;
        gw2[j] = w2g + (size_t)roww * H1 + ((sslot ^ (roww & 7)) * 8);
        lw2[j] = 65536 + rw0 * 128;
    }
#pragma unroll
    for (int j = 0; j < 4; ++j) {
        int r0 = (w * 4 + j) * 8, row = r0 + srow8;
        gw1[j] = w1g + (size_t)row * DIN + ((sslot ^ (row & 7)) * 8);
        lw1[j] = 32768 + r0 * 128;
    }

    // ---- fragment read bases ----
    int baseA[4], swA[4], baseB[4], swB[4], baseB2[2], swB2[2], baseA2[4], swA2[4];
#pragma unroll
    for (int mi = 0; mi < 4; ++mi) {
        int r = wm * 64 + mi * 16 + l15;
        baseA[mi] = r * 128; swA[mi] = (r & 7) << 4;
        baseA2[mi] = r * 512; swA2[mi] = ((r >> 1) & 7) << 4;
    }
#pragma unroll
    for (int nj = 0; nj < 4; ++nj) {
        int r = wn * 64 + nj * 16 + l15;
        baseB[nj] = r * 128; swB[nj] = (r & 7) << 4;
    }
#pragma unroll
    for (int nj = 0; nj < 2; ++nj) {
        int r = wn * 32 + nj * 16 + l15;
        baseB2[nj] = r * 128; swB2[nj] = (r & 7) << 4;
    }

    f32x4 acc1[4][4];
#pragma unroll
    for (int i = 0; i < 4; ++i)
#pragma unroll
        for (int j = 0; j < 4; ++j) acc1[i][j] = (f32x4)0.f;

    // ---- GEMM1: h[128,256] = x[128,512] @ W1t[256,512]^T, 8 chunks of BK=64 ----
    {
        // prologue: stage chunk 0 into buf 0, wait, barrier
#pragma unroll
        for (int j = 0; j < 2; ++j) GLDS16(gx[j], smem + lx[j]);
#pragma unroll
        for (int j = 0; j < 4; ++j) GLDS16(gw1[j], smem + lw1[j]);
        VMCNT0_BARRIER();
        int cur = 0;
        for (int kc = 0; kc < 8; ++kc) {
            // STAGE next chunk first (overlaps with compute below)
            if (kc < 7) {
                int nb = cur ^ 1, ko = (kc + 1) * 64;
#pragma unroll
                for (int j = 0; j < 2; ++j) GLDS16(gx[j] + ko, smem + nb * 16384 + lx[j]);
#pragma unroll
                for (int j = 0; j < 4; ++j) GLDS16(gw1[j] + ko, smem + nb * 32768 + lw1[j]);
            }
            const int xo = cur * 16384;
            const int wo = 32768 + cur * 32768;
#pragma unroll
            for (int kk = 0; kk < 2; ++kk) {
                const int kb = kk * 64 + q16;
                s16x8 af[4], bf[4];
#pragma unroll
                for (int mi = 0; mi < 4; ++mi)
                    af[mi] = *(const s16x8*)(smem + xo + baseA[mi] + (kb ^ swA[mi]));
#pragma unroll
                for (int nj = 0; nj < 4; ++nj)
                    bf[nj] = *(const s16x8*)(smem + wo + baseB[nj] + (kb ^ swB[nj]));
#pragma unroll
                for (int mi = 0; mi < 4; ++mi)
#pragma unroll
                    for (int nj = 0; nj < 4; ++nj)
                        acc1[mi][nj] = __builtin_amdgcn_mfma_f32_16x16x32_bf16(af[mi], bf[nj], acc1[mi][nj], 0, 0, 0);
            }
            // drain our loads (they had the whole compute to land), then raw barrier
            VMCNT0_BARRIER();
            cur ^= 1;
        }
    }

    // ---- stage W2 chunk 0 (into [64K,80K), free now), then write h to LDS ----
#pragma unroll
    for (int j = 0; j < 2; ++j) GLDS16(gw2[j], smem + lw2[j]);
#pragma unroll
    for (int mi = 0; mi < 4; ++mi)
#pragma unroll
        for (int nj = 0; nj < 4; ++nj) {
            int col = wn * 64 + nj * 16 + l15;
            float bias = b1p[col];
#pragma unroll
            for (int r = 0; r < 4; ++r) {
                int row = wm * 64 + mi * 16 + q * 4 + r;
                float v = acc1[mi][nj][r] + bias;
                *(u16*)(smem + row * 512 + ((col * 2) ^ (((row >> 1) & 7) << 4))) = f2bf(v > 0.f ? v : 0.f);
            }
        }
    __syncthreads();   // drains h ds_writes + w2 chunk0 GLDS

    // ---- GEMM2: o[128,128] = h[128,256] @ W2t[128,256]^T, 4 chunks of BK=64 ----
    f32x4 acc2[4][2];
#pragma unroll
    for (int i = 0; i < 4; ++i)
#pragma unroll
        for (int j = 0; j < 2; ++j) acc2[i][j] = (f32x4)0.f;
    int c2 = 0;
    for (int kc = 0; kc < 4; ++kc) {
        if (kc < 3) {
            int nb = c2 ^ 1, ko = (kc + 1) * 64;
#pragma unroll
            for (int j = 0; j < 2; ++j) GLDS16(gw2[j] + ko, smem + (nb ? 16384 : 0) + lw2[j]);
        }
        const int wo = c2 * 16384;
#pragma unroll
        for (int kk = 0; kk < 2; ++kk) {
            const int kb = kk * 64 + q16;
            const int khb = kc * 128 + kb;
            s16x8 a2[4], b2[2];
#pragma unroll
            for (int mi = 0; mi < 4; ++mi)
                a2[mi] = *(const s16x8*)(smem + baseA2[mi] + (khb ^ swA2[mi]));
#pragma unroll
            for (int nj = 0; nj < 2; ++nj)
                b2[nj] = *(const s16x8*)(smem + 65536 + wo + baseB2[nj] + (kb ^ swB2[nj]));
#pragma unroll
            for (int mi = 0; mi < 4; ++mi)
#pragma unroll
                for (int nj = 0; nj < 2; ++nj)
                    acc2[mi][nj] = __builtin_amdgcn_mfma_f32_16x16x32_bf16(a2[mi], b2[nj], acc2[mi][nj], 0, 0, 0);
        }
        VMCNT0_BARRIER();
        c2 ^= 1;
    }

    // ---- epilogue: relu(acc2 + b2) -> eout[e][b][h] bf16 ----
    u16* eo = eout + ((size_t)e * NB + m0) * H2;
#pragma unroll
    for (int mi = 0; mi < 4; ++mi)
#pragma unroll
        for (int nj = 0; nj < 2; ++nj) {
            int col = wn * 32 + nj * 16 + l15;
            float bias = b2p[col];
#pragma unroll
            for (int r = 0; r < 4; ++r) {
                int row = wm * 64 + mi * 16 + q * 4 + r;
                float v = acc2[mi][nj][r] + bias;
                eo[(size_t)row * H2 + col] = f2bf(v > 0.f ? v : 0.f);
            }
        }
}

// ---------------- gate kernel ----------------
__global__ __launch_bounds__(256) void k_gate(
    const u16* __restrict__ xb, const u16* __restrict__ gw1t,
    const float* __restrict__ gb1, const float* __restrict__ gw2, const float* __restrict__ gb2,
    float* __restrict__ gates)
{
    __shared__ __align__(16) char smem[51200];
    u16* xs  = reinterpret_cast<u16*>(smem);
    u16* g1s = reinterpret_cast<u16*>(smem) + 4608;
    float* ghs = reinterpret_cast<float*>(smem);

    int m0 = blockIdx.x * 64;
    int tid = threadIdx.x;
    int w = tid >> 6, lane = tid & 63;
    int wm = w & 1, wn = w >> 1;
    int l15 = lane & 15, lk = (lane >> 4) * 8, lr4 = (lane >> 4) * 4;

    f32x4 acc[2][6];
#pragma unroll
    for (int i = 0; i < 2; ++i)
#pragma unroll
        for (int j = 0; j < 6; ++j) acc[i][j] = (f32x4)0.f;

    const u16* xg = xb + (size_t)m0 * DIN;
    int srow = tid >> 3, su = (tid & 7) * 8;
    for (int kc = 0; kc < DIN / 64; ++kc) {
#pragma unroll
        for (int it = 0; it < 2; ++it) {
            int rr = srow + it * 32;
            *reinterpret_cast<uint4*>(&xs[rr * 72 + su]) =
                *reinterpret_cast<const uint4*>(xg + (size_t)rr * DIN + kc * 64 + su);
        }
#pragma unroll
        for (int it = 0; it < 6; ++it) {
            int rr = srow + it * 32;
            *reinterpret_cast<uint4*>(&g1s[rr * 72 + su]) =
                *reinterpret_cast<const uint4*>(gw1t + (size_t)rr * DIN + kc * 64 + su);
        }
        __syncthreads();
        s16x8 af[2][2], bfr[6][2];
#pragma unroll
        for (int mi = 0; mi < 2; ++mi)
#pragma unroll
            for (int kk = 0; kk < 2; ++kk)
                af[mi][kk] = *reinterpret_cast<const s16x8*>(&xs[(wm * 32 + mi * 16 + l15) * 72 + kk * 32 + lk]);
#pragma unroll
        for (int nj = 0; nj < 6; ++nj)
#pragma unroll
            for (int kk = 0; kk < 2; ++kk)
                bfr[nj][kk] = *reinterpret_cast<const s16x8*>(&g1s[(wn * 96 + nj * 16 + l15) * 72 + kk * 32 + lk]);
#pragma unroll
        for (int kk = 0; kk < 2; ++kk)
#pragma unroll
            for (int mi = 0; mi < 2; ++mi)
#pragma unroll
                for (int nj = 0; nj < 6; ++nj)
                    acc[mi][nj] = __builtin_amdgcn_mfma_f32_16x16x32_bf16(af[mi][kk], bfr[nj][kk], acc[mi][nj], 0, 0, 0);
        __syncthreads();
    }
#pragma unroll
    for (int mi = 0; mi < 2; ++mi)
#pragma unroll
        for (int nj = 0; nj < 6; ++nj) {
            int col = wn * 96 + nj * 16 + l15;
            float bias = gb1[col];
#pragma unroll
            for (int r = 0; r < 4; ++r) {
                int row = wm * 32 + mi * 16 + lr4 + r;
                float v = acc[mi][nj][r] + bias;
                ghs[row * 200 + col] = v > 0.f ? v : 0.f;
            }
        }
    __syncthreads();

    if (tid < 192) {
        int tt = tid >> 6, rr = tid & 63;
        float logit[NETOT];
#pragma unroll
        for (int e2 = 0; e2 < NETOT; ++e2) logit[e2] = gb2[tt * NETOT + e2];
        const float* g2 = gw2 + tt * NGH * NETOT;
        const float* gr = &ghs[rr * 200 + tt * 64];
        for (int g = 0; g < NGH; ++g) {
            float v = gr[g];
#pragma unroll
            for (int e2 = 0; e2 < NETOT; ++e2) logit[e2] += v * g2[g * NETOT + e2];
        }
        float m = logit[0];
#pragma unroll
        for (int e2 = 1; e2 < NETOT; ++e2) m = fmaxf(m, logit[e2]);
        float s = 0.f, p[NETOT];
#pragma unroll
        for (int e2 = 0; e2 < NETOT; ++e2) { p[e2] = __expf(logit[e2] - m); s += p[e2]; }
        float inv = 1.f / s;
        float* go = gates + (size_t)(m0 + rr) * (NT * NETOT) + tt * NETOT;
#pragma unroll
        for (int e2 = 0; e2 < NETOT; ++e2) go[e2] = p[e2] * inv;
    }
}

// ---------------- combine ----------------
__global__ __launch_bounds__(256) void k_combine(
    const u16* __restrict__ eout, const float* __restrict__ gates, float* __restrict__ out)
{
    int tid = threadIdx.x;
    int lr = tid >> 5, hq = tid & 31;
    int b = blockIdx.x * 8 + lr;
    int h0 = hq * 4;
    const float* g = gates + (size_t)b * (NT * NETOT);
    float o0[4] = {0, 0, 0, 0}, o1[4] = {0, 0, 0, 0}, o2[4] = {0, 0, 0, 0};
#pragma unroll
    for (int e = 0; e < NE; ++e) {
        ushort4 ev = *reinterpret_cast<const ushort4*>(&eout[((size_t)e * NB + b) * H2 + h0]);
        float v0 = bf2f(ev.x), v1 = bf2f(ev.y), v2 = bf2f(ev.z), v3 = bf2f(ev.w);
        if (e < 12) {
            float wa = g[e], wb = g[NETOT + e], wc = g[2 * NETOT + e];
            o0[0] += wa * v0; o0[1] += wa * v1; o0[2] += wa * v2; o0[3] += wa * v3;
            o1[0] += wb * v0; o1[1] += wb * v1; o1[2] += wb * v2; o1[3] += wb * v3;
            o2[0] += wc * v0; o2[1] += wc * v1; o2[2] += wc * v2; o2[3] += wc * v3;
        } else {
            int t = (e - 12) >> 1, te = (e - 12) & 1;
            float wt = g[t * NETOT + 12 + te];
            float* ot = (t == 0) ? o0 : (t == 1) ? o1 : o2;
            ot[0] += wt * v0; ot[1] += wt * v1; ot[2] += wt * v2; ot[3] += wt * v3;
        }
    }
    size_t base = (size_t)b * H2 + h0;
    *reinterpret_cast<float4*>(&out[0 * (size_t)NB * H2 + base]) = make_float4(o0[0], o0[1], o0[2], o0[3]);
    *reinterpret_cast<float4*>(&out[1 * (size_t)NB * H2 + base]) = make_float4(o1[0], o1[1], o1[2], o1[3]);
    *reinterpret_cast<float4*>(&out[2 * (size_t)NB * H2 + base]) = make_float4(o2[0], o2[1], o2[2], o2[3]);
}

extern "C" void kernel_launch(void* const* d_in, const int* in_sizes, int n_in,
                              void* d_out, int out_size, void* d_ws, size_t ws_size,
                              hipStream_t stream)
{
    const float* x   = (const float*)d_in[0];
    const float* sW1 = (const float*)d_in[2];
    const float* sb1 = (const float*)d_in[3];
    const float* sW2 = (const float*)d_in[4];
    const float* sb2 = (const float*)d_in[5];
    const float* dW1 = (const float*)d_in[6];
    const float* db1 = (const float*)d_in[7];
    const float* dW2 = (const float*)d_in[8];
    const float* db2 = (const float*)d_in[9];
    const float* tW1 = (const float*)d_in[10];
    const float* tb1 = (const float*)d_in[11];
    const float* tW2 = (const float*)d_in[12];
    const float* tb2 = (const float*)d_in[13];
    const float* gW1 = (const float*)d_in[14];
    const float* gb1 = (const float*)d_in[15];
    const float* gW2 = (const float*)d_in[16];
    const float* gb2 = (const float*)d_in[17];

    char* ws = (char*)d_ws;
    u16*  xb    = (u16*)(ws + 0);
    u16*  w1t   = (u16*)(ws + 16777216);
    u16*  w2t   = (u16*)(ws + 21495808);
    u16*  gw1t  = (u16*)(ws + 22675456);
    float* gates = (float*)(ws + 22872064);
    u16*  eout  = (u16*)(ws + 25624576);

    k_prep<<<dim3(8936), dim3(256), 0, stream>>>(x, xb, sW1, dW1, tW1, sW2, dW2, tW2, gW1, w1t, w2t, gw1t);
    k_gate<<<dim3(NB / 64), dim3(256), 0, stream>>>(xb, gw1t, gb1, gW2, gb2, gates);
    k_expert<<<dim3(NE * (NB / 128)), dim3(512), 0, stream>>>(xb, w1t, w2t, sb1, db1, tb1, sb2, db2, tb2, eout);
    k_combine<<<dim3(NB / 8), dim3(256), 0, stream>>>(eout, gates, (float*)d_out);
}

// Round 5
// 182.794 us; speedup vs baseline: 1.2944x; 1.0184x over previous
//
#include <hip/hip_runtime.h>
#include <hip/hip_bf16.h>

#define NB 16384
#define DIN 512
#define H1 256
#define H2 128
#define NE 18
#define NT 3
#define NGH 64
#define NETOT 14

typedef float f32x4 __attribute__((ext_vector_type(4)));
typedef short s16x8 __attribute__((ext_vector_type(8)));
typedef unsigned short u16;
typedef unsigned int u32;

__device__ __forceinline__ u16 f2bf(float f) {
    union { float f; u32 u; } v; v.f = f;
    u32 r = v.u + 0x7fffu + ((v.u >> 16) & 1u);
    return (u16)(r >> 16);
}
__device__ __forceinline__ float bf2f(u16 u) {
    union { u32 u; float f; } v; v.u = ((u32)u) << 16;
    return v.f;
}

// async global->LDS, 16B per lane. lds ptr wave-uniform; HW writes lane i at lds+16*i.
#define GLDS16(g, l) __builtin_amdgcn_global_load_lds((const u32*)(g), (u32*)(l), 16, 0, 0)
#define VMCNT0_BARRIER() do { asm volatile("s_waitcnt vmcnt(0)" ::: "memory"); __builtin_amdgcn_s_barrier(); } while (0)

// ---------------- prep: x cvt + ALL weight transposes, one launch ----------------
__global__ __launch_bounds__(256) void k_prep(
    const float* __restrict__ x, u16* __restrict__ xb,
    const float* __restrict__ sW1, const float* __restrict__ dW1, const float* __restrict__ tW1,
    const float* __restrict__ sW2, const float* __restrict__ dW2, const float* __restrict__ tW2,
    const float* __restrict__ gW1, u16* __restrict__ w1t, u16* __restrict__ w2t, u16* __restrict__ gw1t)
{
    __shared__ float lds[64 * 65];
    int bx = blockIdx.x;
    if (bx < 8192) {
        int i = (bx * 256 + threadIdx.x) * 4;
        float4 v = *reinterpret_cast<const float4*>(x + i);
        ushort4 o;
        o.x = f2bf(v.x); o.y = f2bf(v.y); o.z = f2bf(v.z); o.w = f2bf(v.w);
        *reinterpret_cast<ushort4*>(xb + i) = o;
        return;
    }
    int b = bx - 8192;
    const float* src; u16* dst; int K, N, k0, n0;
    if (b < 576) {
        int e = b >> 5, tile = b & 31;
        src = (e < 4) ? sW1 + (size_t)e * DIN * H1 : (e < 12) ? dW1 + (size_t)(e - 4) * DIN * H1
                                                              : tW1 + (size_t)(e - 12) * DIN * H1;
        dst = w1t + (size_t)e * H1 * DIN; K = DIN; N = H1;
        k0 = (tile >> 2) * 64; n0 = (tile & 3) * 64;
    } else if (b < 720) {
        int b2 = b - 576; int e = b2 >> 3, tile = b2 & 7;
        src = (e < 4) ? sW2 + (size_t)e * H1 * H2 : (e < 12) ? dW2 + (size_t)(e - 4) * H1 * H2
                                                             : tW2 + (size_t)(e - 12) * H1 * H2;
        dst = w2t + (size_t)e * H2 * H1; K = H1; N = H2;
        k0 = (tile >> 1) * 64; n0 = (tile & 1) * 64;
    } else {
        int b3 = b - 720; int t = b3 >> 3, tile = b3 & 7;
        src = gW1 + (size_t)t * DIN * NGH; dst = gw1t + (size_t)t * NGH * DIN; K = DIN; N = NGH;
        k0 = tile * 64; n0 = 0;
    }
    int t = threadIdx.x;
#pragma unroll
    for (int i = 0; i < 16; ++i) {
        int idx = i * 256 + t;
        int kk = idx >> 6, nn = idx & 63;
        lds[kk * 65 + nn] = src[(size_t)(k0 + kk) * N + n0 + nn];
    }
    __syncthreads();
#pragma unroll
    for (int i = 0; i < 16; ++i) {
        int idx = i * 256 + t;
        int nn = idx >> 6, kk = idx & 63;
        dst[(size_t)(n0 + nn) * K + k0 + kk] = f2bf(lds[kk * 65 + nn]);
    }
}

// ---------------- fused 2-layer expert kernel, 256x256 tile ----------------
// grid: 18 experts * 64 m-blocks (256 rows), XCD-swizzled. 512 threads = 8 waves (2M x 4N),
// wave tile 128x64. GEMM1: K=512 in 8 BK=64 tiles, double-buffered (2x64KB), front-loaded
// GLDS + per-kk {12 ds_read -> setprio(1) -> 32 MFMA -> setprio(0)}. GEMM2 fused via
// hs[256][256] bf16 swizzled in LDS (overlaps staging), W2 single-buffered @128K.
__global__ __launch_bounds__(512, 2) void k_expert(
    const u16* __restrict__ xb, const u16* __restrict__ w1t, const u16* __restrict__ w2t,
    const float* __restrict__ sb1, const float* __restrict__ db1, const float* __restrict__ tb1,
    const float* __restrict__ sb2, const float* __restrict__ db2, const float* __restrict__ tb2,
    u16* __restrict__ eout)
{
    // LDS map: buf c: A @ c*65536 (32KB), B @ c*65536+32768 (32KB)  -> [0,128K)
    //          phase2: hs @ 0 (128KB, [256][512B] swizzled), w2s @ 131072 (16KB)
    __shared__ __align__(128) char smem[147456];

    const int bx = blockIdx.x;
    const int nbk = (bx & 7) * 144 + (bx >> 3);   // bijective XCD swizzle (1152 % 8 == 0)
    const int e  = nbk >> 6;
    const int m0 = (nbk & 63) * 256;
    const int tid = threadIdx.x;
    const int w = tid >> 6, lane = tid & 63;
    const int wm = w & 1, wn = w >> 1;            // 2M x 4N
    const int l15 = lane & 15, q = lane >> 4;
    const int swzl = (l15 & 7) << 4;
    int kbs[2]; kbs[0] = (q * 16) ^ swzl; kbs[1] = (64 + q * 16) ^ swzl;
    const int srow8 = lane >> 3, sslot = lane & 7;

    const u16* xg  = xb + (size_t)m0 * DIN;
    const u16* w1g = w1t + (size_t)e * H1 * DIN;
    const u16* w2g = w2t + (size_t)e * H2 * H1;
    const float* b1p = (e < 4) ? sb1 + e * H1 : (e < 12) ? db1 + (e - 4) * H1 : tb1 + (e - 12) * H1;
    const float* b2p = (e < 4) ? sb2 + e * H2 : (e < 12) ? db2 + (e - 4) * H2 : tb2 + (e - 12) * H2;

    // ---- staging addresses (per-lane inverse-swizzled global, wave-uniform LDS) ----
    const u16* gxa[4]; const u16* gxb[4]; int lxa[4], lxb[4];
#pragma unroll
    for (int j = 0; j < 4; ++j) {
        int r0 = j * 64 + w * 8, row = r0 + srow8;
        gxa[j] = xg  + (size_t)row * DIN + ((sslot ^ srow8) * 8);
        gxb[j] = w1g + (size_t)row * DIN + ((sslot ^ srow8) * 8);
        lxa[j] = r0 * 128;
        lxb[j] = 32768 + r0 * 128;
    }
    const u16* gw2v[2]; int lw2[2];
#pragma unroll
    for (int j = 0; j < 2; ++j) {
        int r0 = j * 64 + w * 8, row = r0 + srow8;
        gw2v[j] = w2g + (size_t)row * H1 + ((sslot ^ srow8) * 8);
        lw2[j] = 131072 + r0 * 128;
    }

    // ---- fragment base byte-offsets ----
    const int rA  = wm * 16384 + l15 * 128;            // + c*65536 + mi*2048 + kbs[kk]
    const int rB  = 32768 + wn * 8192 + l15 * 128;     // + c*65536 + nj*2048 + kbs[kk]
    const int rH  = wm * 65536 + l15 * 512;            // + mi*8192 + kt*128 + kbs[kk]
    const int rW2 = 131072 + wn * 4096 + l15 * 128;    // + nj*2048 + kbs[kk]

    f32x4 acc1[8][4];
#pragma unroll
    for (int i = 0; i < 8; ++i)
#pragma unroll
        for (int j = 0; j < 4; ++j) acc1[i][j] = (f32x4)0.f;

    // ---- GEMM1: h[256,256] = x[256,512] @ W1t[256,512]^T ----
#pragma unroll
    for (int j = 0; j < 4; ++j) GLDS16(gxa[j], smem + lxa[j]);
#pragma unroll
    for (int j = 0; j < 4; ++j) GLDS16(gxb[j], smem + lxb[j]);
    VMCNT0_BARRIER();

    for (int t = 0; t < 8; ++t) {
        const int cb = (t & 1) * 65536;
        if (t < 7) {
            const int nbuf = ((t & 1) ^ 1) * 65536, ko = (t + 1) * 64;
#pragma unroll
            for (int j = 0; j < 4; ++j) GLDS16(gxa[j] + ko, smem + nbuf + lxa[j]);
#pragma unroll
            for (int j = 0; j < 4; ++j) GLDS16(gxb[j] + ko, smem + nbuf + lxb[j]);
        } else {
            GLDS16(gw2v[0], smem + lw2[0]);   // prefetch W2 k-tile 0 (region disjoint)
            GLDS16(gw2v[1], smem + lw2[1]);
        }
#pragma unroll
        for (int kk = 0; kk < 2; ++kk) {
            s16x8 bfr[4], afr[8];
#pragma unroll
            for (int nj = 0; nj < 4; ++nj)
                bfr[nj] = *(const s16x8*)(smem + cb + rB + nj * 2048 + kbs[kk]);
#pragma unroll
            for (int mi = 0; mi < 8; ++mi)
                afr[mi] = *(const s16x8*)(smem + cb + rA + mi * 2048 + kbs[kk]);
            __builtin_amdgcn_s_setprio(1);
#pragma unroll
            for (int mi = 0; mi < 8; ++mi)
#pragma unroll
                for (int nj = 0; nj < 4; ++nj)
                    acc1[mi][nj] = __builtin_amdgcn_mfma_f32_16x16x32_bf16(afr[mi], bfr[nj], acc1[mi][nj], 0, 0, 0);
            __builtin_amdgcn_s_setprio(0);
        }
        VMCNT0_BARRIER();
    }

    // ---- h = relu(acc1+b1) -> hs (swizzled [256][512B]) ----
#pragma unroll
    for (int mi = 0; mi < 8; ++mi)
#pragma unroll
        for (int nj = 0; nj < 4; ++nj) {
            int col = wn * 64 + nj * 16 + l15;
            int col2 = col * 2;
            float bias = b1p[col];
#pragma unroll
            for (int r = 0; r < 4; ++r) {
                int row = wm * 128 + mi * 16 + q * 4 + r;
                float v = acc1[mi][nj][r] + bias;
                *(u16*)(smem + row * 512 + (col2 ^ ((row & 7) << 4))) = f2bf(v > 0.f ? v : 0.f);
            }
        }
    __syncthreads();   // drains ds_writes + the W2 tile0 GLDS

    // ---- GEMM2: o[256,128] = h[256,256] @ W2t[128,256]^T, 4 tiles BK=64 ----
    f32x4 acc2[8][2];
#pragma unroll
    for (int i = 0; i < 8; ++i)
#pragma unroll
        for (int j = 0; j < 2; ++j) acc2[i][j] = (f32x4)0.f;
    for (int kt = 0; kt < 4; ++kt) {
#pragma unroll
        for (int kk = 0; kk < 2; ++kk) {
            s16x8 b2[2], hf[8];
#pragma unroll
            for (int nj = 0; nj < 2; ++nj)
                b2[nj] = *(const s16x8*)(smem + rW2 + nj * 2048 + kbs[kk]);
#pragma unroll
            for (int mi = 0; mi < 8; ++mi)
                hf[mi] = *(const s16x8*)(smem + rH + mi * 8192 + kt * 128 + kbs[kk]);
            __builtin_amdgcn_s_setprio(1);
#pragma unroll
            for (int mi = 0; mi < 8; ++mi)
#pragma unroll
                for (int nj = 0; nj < 2; ++nj)
                    acc2[mi][nj] = __builtin_amdgcn_mfma_f32_16x16x32_bf16(hf[mi], b2[nj], acc2[mi][nj], 0, 0, 0);
            __builtin_amdgcn_s_setprio(0);
        }
        if (kt < 3) {
            __builtin_amdgcn_s_barrier();     // all waves done reading w2s tile kt
            GLDS16(gw2v[0] + (kt + 1) * 64, smem + lw2[0]);
            GLDS16(gw2v[1] + (kt + 1) * 64, smem + lw2[1]);
            VMCNT0_BARRIER();
        }
    }

    // ---- epilogue: relu(acc2+b2) -> eout[e][b][h] bf16 ----
    u16* eo = eout + ((size_t)e * NB + m0) * H2;
#pragma unroll
    for (int mi = 0; mi < 8; ++mi)
#pragma unroll
        for (int nj = 0; nj < 2; ++nj) {
            int col = wn * 32 + nj * 16 + l15;
            float bias = b2p[col];
#pragma unroll
            for (int r = 0; r < 4; ++r) {
                int row = wm * 128 + mi * 16 + q * 4 + r;
                float v = acc2[mi][nj][r] + bias;
                eo[(size_t)row * H2 + col] = f2bf(v > 0.f ? v : 0.f);
            }
        }
}

// ---------------- gate kernel ----------------
__global__ __launch_bounds__(256) void k_gate(
    const u16* __restrict__ xb, const u16* __restrict__ gw1t,
    const float* __restrict__ gb1, const float* __restrict__ gw2, const float* __restrict__ gb2,
    float* __restrict__ gates)
{
    __shared__ __align__(16) char smem[51200];
    u16* xs  = reinterpret_cast<u16*>(smem);
    u16* g1s = reinterpret_cast<u16*>(smem) + 4608;
    float* ghs = reinterpret_cast<float*>(smem);

    int m0 = blockIdx.x * 64;
    int tid = threadIdx.x;
    int w = tid >> 6, lane = tid & 63;
    int wm = w & 1, wn = w >> 1;
    int l15 = lane & 15, lk = (lane >> 4) * 8, lr4 = (lane >> 4) * 4;

    f32x4 acc[2][6];
#pragma unroll
    for (int i = 0; i < 2; ++i)
#pragma unroll
        for (int j = 0; j < 6; ++j) acc[i][j] = (f32x4)0.f;

    const u16* xg = xb + (size_t)m0 * DIN;
    int srow = tid >> 3, su = (tid & 7) * 8;
    for (int kc = 0; kc < DIN / 64; ++kc) {
#pragma unroll
        for (int it = 0; it < 2; ++it) {
            int rr = srow + it * 32;
            *reinterpret_cast<uint4*>(&xs[rr * 72 + su]) =
                *reinterpret_cast<const uint4*>(xg + (size_t)rr * DIN + kc * 64 + su);
        }
#pragma unroll
        for (int it = 0; it < 6; ++it) {
            int rr = srow + it * 32;
            *reinterpret_cast<uint4*>(&g1s[rr * 72 + su]) =
                *reinterpret_cast<const uint4*>(gw1t + (size_t)rr * DIN + kc * 64 + su);
        }
        __syncthreads();
        s16x8 af[2][2], bfr[6][2];
#pragma unroll
        for (int mi = 0; mi < 2; ++mi)
#pragma unroll
            for (int kk = 0; kk < 2; ++kk)
                af[mi][kk] = *reinterpret_cast<const s16x8*>(&xs[(wm * 32 + mi * 16 + l15) * 72 + kk * 32 + lk]);
#pragma unroll
        for (int nj = 0; nj < 6; ++nj)
#pragma unroll
            for (int kk = 0; kk < 2; ++kk)
                bfr[nj][kk] = *reinterpret_cast<const s16x8*>(&g1s[(wn * 96 + nj * 16 + l15) * 72 + kk * 32 + lk]);
#pragma unroll
        for (int kk = 0; kk < 2; ++kk)
#pragma unroll
            for (int mi = 0; mi < 2; ++mi)
#pragma unroll
                for (int nj = 0; nj < 6; ++nj)
                    acc[mi][nj] = __builtin_amdgcn_mfma_f32_16x16x32_bf16(af[mi][kk], bfr[nj][kk], acc[mi][nj], 0, 0, 0);
        __syncthreads();
    }
#pragma unroll
    for (int mi = 0; mi < 2; ++mi)
#pragma unroll
        for (int nj = 0; nj < 6; ++nj) {
            int col = wn * 96 + nj * 16 + l15;
            float bias = gb1[col];
#pragma unroll
            for (int r = 0; r < 4; ++r) {
                int row = wm * 32 + mi * 16 + lr4 + r;
                float v = acc[mi][nj][r] + bias;
                ghs[row * 200 + col] = v > 0.f ? v : 0.f;
            }
        }
    __syncthreads();

    if (tid < 192) {
        int tt = tid >> 6, rr = tid & 63;
        float logit[NETOT];
#pragma unroll
        for (int e2 = 0; e2 < NETOT; ++e2) logit[e2] = gb2[tt * NETOT + e2];
        const float* g2 = gw2 + tt * NGH * NETOT;
        const float* gr = &ghs[rr * 200 + tt * 64];
        for (int g = 0; g < NGH; ++g) {
            float v = gr[g];
#pragma unroll
            for (int e2 = 0; e2 < NETOT; ++e2) logit[e2] += v * g2[g * NETOT + e2];
        }
        float m = logit[0];
#pragma unroll
        for (int e2 = 1; e2 < NETOT; ++e2) m = fmaxf(m, logit[e2]);
        float s = 0.f, p[NETOT];
#pragma unroll
        for (int e2 = 0; e2 < NETOT; ++e2) { p[e2] = __expf(logit[e2] - m); s += p[e2]; }
        float inv = 1.f / s;
        float* go = gates + (size_t)(m0 + rr) * (NT * NETOT) + tt * NETOT;
#pragma unroll
        for (int e2 = 0; e2 < NETOT; ++e2) go[e2] = p[e2] * inv;
    }
}

// ---------------- combine ----------------
__global__ __launch_bounds__(256) void k_combine(
    const u16* __restrict__ eout, const float* __restrict__ gates, float* __restrict__ out)
{
    int tid = threadIdx.x;
    int lr = tid >> 5, hq = tid & 31;
    int b = blockIdx.x * 8 + lr;
    int h0 = hq * 4;
    const float* g = gates + (size_t)b * (NT * NETOT);
    float o0[4] = {0, 0, 0, 0}, o1[4] = {0, 0, 0, 0}, o2[4] = {0, 0, 0, 0};
#pragma unroll
    for (int e = 0; e < NE; ++e) {
        ushort4 ev = *reinterpret_cast<const ushort4*>(&eout[((size_t)e * NB + b) * H2 + h0]);
        float v0 = bf2f(ev.x), v1 = bf2f(ev.y), v2 = bf2f(ev.z), v3 = bf2f(ev.w);
        if (e < 12) {
            float wa = g[e], wb = g[NETOT + e], wc = g[2 * NETOT + e];
            o0[0] += wa * v0; o0[1] += wa * v1; o0[2] += wa * v2; o0[3] += wa * v3;
            o1[0] += wb * v0; o1[1] += wb * v1; o1[2] += wb * v2; o1[3] += wb * v3;
            o2[0] += wc * v0; o2[1] += wc * v1; o2[2] += wc * v2; o2[3] += wc * v3;
        } else {
            int t = (e - 12) >> 1, te = (e - 12) & 1;
            float wt = g[t * NETOT + 12 + te];
            float* ot = (t == 0) ? o0 : (t == 1) ? o1 : o2;
            ot[0] += wt * v0; ot[1] += wt * v1; ot[2] += wt * v2; ot[3] += wt * v3;
        }
    }
    size_t base = (size_t)b * H2 + h0;
    *reinterpret_cast<float4*>(&out[0 * (size_t)NB * H2 + base]) = make_float4(o0[0], o0[1], o0[2], o0[3]);
    *reinterpret_cast<float4*>(&out[1 * (size_t)NB * H2 + base]) = make_float4(o1[0], o1[1], o1[2], o1[3]);
    *reinterpret_cast<float4*>(&out[2 * (size_t)NB * H2 + base]) = make_float4(o2[0], o2[1], o2[2], o2[3]);
}

extern "C" void kernel_launch(void* const* d_in, const int* in_sizes, int n_in,
                              void* d_out, int out_size, void* d_ws, size_t ws_size,
                              hipStream_t stream)
{
    const float* x   = (const float*)d_in[0];
    const float* sW1 = (const float*)d_in[2];
    const float* sb1 = (const float*)d_in[3];
    const float* sW2 = (const float*)d_in[4];
    const float* sb2 = (const float*)d_in[5];
    const float* dW1 = (const float*)d_in[6];
    const float* db1 = (const float*)d_in[7];
    const float* dW2 = (const float*)d_in[8];
    const float* db2 = (const float*)d_in[9];
    const float* tW1 = (const float*)d_in[10];
    const float* tb1 = (const float*)d_in[11];
    const float* tW2 = (const float*)d_in[12];
    const float* tb2 = (const float*)d_in[13];
    const float* gW1 = (const float*)d_in[14];
    const float* gb1 = (const float*)d_in[15];
    const float* gW2 = (const float*)d_in[16];
    const float* gb2 = (const float*)d_in[17];

    char* ws = (char*)d_ws;
    u16*  xb    = (u16*)(ws + 0);
    u16*  w1t   = (u16*)(ws + 16777216);
    u16*  w2t   = (u16*)(ws + 21495808);
    u16*  gw1t  = (u16*)(ws + 22675456);
    float* gates = (float*)(ws + 22872064);
    u16*  eout  = (u16*)(ws + 25624576);

    k_prep<<<dim3(8936), dim3(256), 0, stream>>>(x, xb, sW1, dW1, tW1, sW2, dW2, tW2, gW1, w1t, w2t, gw1t);
    k_gate<<<dim3(NB / 64), dim3(256), 0, stream>>>(xb, gw1t, gb1, gW2, gb2, gates);
    k_expert<<<dim3(NE * (NB / 256)), dim3(512), 0, stream>>>(xb, w1t, w2t, sb1, db1, tb1, sb2, db2, tb2, eout);
    k_combine<<<dim3(NB / 8), dim3(256), 0, stream>>>(eout, gates, (float*)d_out);
}